// Round 4
// baseline (51.832 us; speedup 1.0000x reference)
//
#include <hip/hip_runtime.h>

// VectorQuantization: x (32,64,64,64) f32, embedding (512,64) f32
// out = [quantized_ste (8388608 f32)] ++ [loss (1 f32)]
//
// score[k,n] = e2[k] - 2*dot(e_k, x_n); argmin_k; gather; loss=1.25*mean dist.
// bf16 3-pass MFMA (hi*hi + lo*hi + hi*lo), packed top-2 + fp64 refine.
// Round 4: 64 vec/wave (4 acc chains) -> LDS/kt halved, BLK=512 (256 VGPR
// budget), per-wave gather epilogue (no block barrier before writes).

#define C_DIM 64
#define K_EMB 512
#define NVEC (32 * 64 * 64)     // 131072
#define BLK 512                 // 8 waves
#define VPW 64                  // vectors per wave
#define NPB 512                 // vectors per block
#define GRID (NVEC / NPB)       // 256 = 1 block/CU
#define KT (K_EMB / 16)         // 32 k-tiles
#define NT 4                    // 16-vector groups per wave

typedef __attribute__((ext_vector_type(8))) short bf16x8;
typedef __attribute__((ext_vector_type(4))) float f32x4;

// ws layout (bytes)
#define WS_E2   0
#define WS_EHI  4096
#define WS_ELO  (4096 + 65536)
#define WS_PART (4096 + 2 * 65536)

__device__ inline unsigned short f2bf(float f) {
    unsigned u = __float_as_uint(f);
    u += 0x7FFF + ((u >> 16) & 1);   // RNE
    return (unsigned short)(u >> 16);
}
__device__ inline float bf2f(unsigned short h) {
    return __uint_as_float(((unsigned)h) << 16);
}
__device__ inline bool lessidx(float s, int i, float t, int j) {
    return (s < t) || (s == t && i < j);
}

// ---- prep: e2[k]; frag-linear bf16 hi/lo of (-2*emb) ----
// frag layout: region r = kt*2 + s (s = K-step), lane l holds 8 bf16 =
// A[row = kt*16 + (l&15)][c = 32*s + (l>>4)*8 + j], stored at (r*64+l)*8 shorts.
__global__ __launch_bounds__(512) void vq_prep(const float* __restrict__ emb,
                                               float* __restrict__ e2,
                                               short* __restrict__ ehi,
                                               short* __restrict__ elo) {
    const int t = blockIdx.x * 512 + threadIdx.x;   // 0..4095
    const int l = t & 63;
    const int kt2 = t >> 6;                         // kt*2 + s
    const int row = (kt2 >> 1) * 16 + (l & 15);
    const int cb  = (kt2 & 1) * 32 + (l >> 4) * 8;
    const float* src = emb + row * C_DIM + cb;
    bf16x8 vh, vl;
#pragma unroll
    for (int j = 0; j < 8; ++j) {
        float v = -2.0f * src[j];
        unsigned short h = f2bf(v);
        float hf = bf2f(h);
        unsigned short q = f2bf(v - hf);
        vh[j] = (short)h;
        vl[j] = (short)q;
    }
    *(bf16x8*)(ehi + (size_t)t * 8) = vh;
    *(bf16x8*)(elo + (size_t)t * 8) = vl;

    if (t < K_EMB) {
        const float* r = emb + t * C_DIM;
        float s = 0.f;
#pragma unroll
        for (int c = 0; c < C_DIM; ++c) s += r[c] * r[c];
        e2[t] = s;
    }
}

__global__ __launch_bounds__(BLK, 2) void vq_main(
    const float* __restrict__ x,
    const float* __restrict__ emb,
    const float* __restrict__ e2g,
    const short* __restrict__ ehi_g,
    const short* __restrict__ elo_g,
    float* __restrict__ out,
    double* __restrict__ partials)
{
    __shared__ __align__(16) short s_hi[K_EMB * C_DIM];  // 64 KB, frag-linear
    __shared__ __align__(16) short s_lo[K_EMB * C_DIM];  // 64 KB
    __shared__ __align__(16) float s_e2[K_EMB];          // 2 KB
    __shared__ double s_wsum[BLK / 64];

    const int tid = threadIdx.x;

    // ---- stage tables into LDS (linear copy, coalesced) ----
    {
        const float4* srch = (const float4*)ehi_g;
        const float4* srcl = (const float4*)elo_g;
        float4* dsth = (float4*)s_hi;
        float4* dstl = (float4*)s_lo;
#pragma unroll
        for (int i = 0; i < 16; ++i) dsth[tid + i * BLK] = srch[tid + i * BLK];
#pragma unroll
        for (int i = 0; i < 16; ++i) dstl[tid + i * BLK] = srcl[tid + i * BLK];
        if (tid < K_EMB) s_e2[tid] = e2g[tid];
    }
    __syncthreads();

    const int lane = tid & 63;
    const int wid  = tid >> 6;
    const int lr   = lane & 15;
    const int lh   = lane >> 4;
    const int nbase = blockIdx.x * NPB + wid * VPW;

    // ---- x -> B-fragments (hi/lo), x2 partials ----
    // B-frag: lane l holds B[c = 32*s + (l>>4)*8 + j][n = base + nt*16 + (l&15)]
    bf16x8 xh[NT][2], xl[NT][2];
    float x2p[NT];
#pragma unroll
    for (int nt = 0; nt < NT; ++nt) {
        const int n = nbase + nt * 16 + lr;
        const float* xp = x + (size_t)n * C_DIM;
        x2p[nt] = 0.f;
#pragma unroll
        for (int s = 0; s < 2; ++s) {
            const float* p = xp + s * 32 + lh * 8;
            float4 a = *(const float4*)(p);
            float4 b = *(const float4*)(p + 4);
            float vv[8] = {a.x, a.y, a.z, a.w, b.x, b.y, b.z, b.w};
#pragma unroll
            for (int j = 0; j < 8; ++j) {
                float v = vv[j];
                x2p[nt] += v * v;
                unsigned short h = f2bf(v);
                float hf = bf2f(h);
                unsigned short q = f2bf(v - hf);
                xh[nt][s][j] = (short)h;
                xl[nt][s][j] = (short)q;
            }
        }
    }

    // ---- k-loop: 32 tiles of 16 embeddings; packed branch-free top-2 ----
    // packed = (round_to_7bits(score) & ~127) | (kt*4 + r)   [lane-local idx]
    float pb1[NT], pb2[NT];
#pragma unroll
    for (int nt = 0; nt < NT; ++nt) { pb1[nt] = 1e30f; pb2[nt] = 1e30f; }

    for (int kt = 0; kt < KT; ++kt) {
        const bf16x8* hp = (const bf16x8*)s_hi + kt * 128 + lane;
        const bf16x8* lp = (const bf16x8*)s_lo + kt * 128 + lane;
        bf16x8 ah0 = hp[0], ah1 = hp[64];
        bf16x8 al0 = lp[0], al1 = lp[64];
        float4 ev = *(const float4*)(s_e2 + kt * 16 + lh * 4);
        f32x4 a0 = {ev.x, ev.y, ev.z, ev.w};
        f32x4 a1 = a0, a2 = a0, a3 = a0;

        // 24 MFMAs, 4 independent chains, 6 deep
        a0 = __builtin_amdgcn_mfma_f32_16x16x32_bf16(ah0, xh[0][0], a0, 0, 0, 0);
        a1 = __builtin_amdgcn_mfma_f32_16x16x32_bf16(ah0, xh[1][0], a1, 0, 0, 0);
        a2 = __builtin_amdgcn_mfma_f32_16x16x32_bf16(ah0, xh[2][0], a2, 0, 0, 0);
        a3 = __builtin_amdgcn_mfma_f32_16x16x32_bf16(ah0, xh[3][0], a3, 0, 0, 0);
        a0 = __builtin_amdgcn_mfma_f32_16x16x32_bf16(ah1, xh[0][1], a0, 0, 0, 0);
        a1 = __builtin_amdgcn_mfma_f32_16x16x32_bf16(ah1, xh[1][1], a1, 0, 0, 0);
        a2 = __builtin_amdgcn_mfma_f32_16x16x32_bf16(ah1, xh[2][1], a2, 0, 0, 0);
        a3 = __builtin_amdgcn_mfma_f32_16x16x32_bf16(ah1, xh[3][1], a3, 0, 0, 0);
        a0 = __builtin_amdgcn_mfma_f32_16x16x32_bf16(al0, xh[0][0], a0, 0, 0, 0);
        a1 = __builtin_amdgcn_mfma_f32_16x16x32_bf16(al0, xh[1][0], a1, 0, 0, 0);
        a2 = __builtin_amdgcn_mfma_f32_16x16x32_bf16(al0, xh[2][0], a2, 0, 0, 0);
        a3 = __builtin_amdgcn_mfma_f32_16x16x32_bf16(al0, xh[3][0], a3, 0, 0, 0);
        a0 = __builtin_amdgcn_mfma_f32_16x16x32_bf16(al1, xh[0][1], a0, 0, 0, 0);
        a1 = __builtin_amdgcn_mfma_f32_16x16x32_bf16(al1, xh[1][1], a1, 0, 0, 0);
        a2 = __builtin_amdgcn_mfma_f32_16x16x32_bf16(al1, xh[2][1], a2, 0, 0, 0);
        a3 = __builtin_amdgcn_mfma_f32_16x16x32_bf16(al1, xh[3][1], a3, 0, 0, 0);
        a0 = __builtin_amdgcn_mfma_f32_16x16x32_bf16(ah0, xl[0][0], a0, 0, 0, 0);
        a1 = __builtin_amdgcn_mfma_f32_16x16x32_bf16(ah0, xl[1][0], a1, 0, 0, 0);
        a2 = __builtin_amdgcn_mfma_f32_16x16x32_bf16(ah0, xl[2][0], a2, 0, 0, 0);
        a3 = __builtin_amdgcn_mfma_f32_16x16x32_bf16(ah0, xl[3][0], a3, 0, 0, 0);
        a0 = __builtin_amdgcn_mfma_f32_16x16x32_bf16(ah1, xl[0][1], a0, 0, 0, 0);
        a1 = __builtin_amdgcn_mfma_f32_16x16x32_bf16(ah1, xl[1][1], a1, 0, 0, 0);
        a2 = __builtin_amdgcn_mfma_f32_16x16x32_bf16(ah1, xl[2][1], a2, 0, 0, 0);
        a3 = __builtin_amdgcn_mfma_f32_16x16x32_bf16(ah1, xl[3][1], a3, 0, 0, 0);

        const unsigned kb4 = (unsigned)(kt * 4);
#define PACKMIN(ACC, NTI)                                                          \
        {                                                                          \
            unsigned q0 = ((__float_as_uint(ACC[0]) + 64u) & 0xFFFFFF80u) | (kb4 + 0); \
            unsigned q1 = ((__float_as_uint(ACC[1]) + 64u) & 0xFFFFFF80u) | (kb4 + 1); \
            unsigned q2 = ((__float_as_uint(ACC[2]) + 64u) & 0xFFFFFF80u) | (kb4 + 2); \
            unsigned q3 = ((__float_as_uint(ACC[3]) + 64u) & 0xFFFFFF80u) | (kb4 + 3); \
            float f0 = __uint_as_float(q0), f1 = __uint_as_float(q1);              \
            float f2 = __uint_as_float(q2), f3 = __uint_as_float(q3);              \
            float lo = fminf(f0, f1), hi = fmaxf(f0, f1);                          \
            pb2[NTI] = fminf(fminf(pb2[NTI], fmaxf(pb1[NTI], lo)), hi);            \
            pb1[NTI] = fminf(pb1[NTI], lo);                                        \
            lo = fminf(f2, f3); hi = fmaxf(f2, f3);                                \
            pb2[NTI] = fminf(fminf(pb2[NTI], fmaxf(pb1[NTI], lo)), hi);            \
            pb1[NTI] = fminf(pb1[NTI], lo);                                        \
        }
        PACKMIN(a0, 0)
        PACKMIN(a1, 1)
        PACKMIN(a2, 2)
        PACKMIN(a3, 3)
#undef PACKMIN
    }

    // ---- per-nt: unpack, cross-lane merge, refine, gather, loss ----
    double dsum = 0.0;
#pragma unroll
    for (int nt = 0; nt < NT; ++nt) {
        unsigned u1 = __float_as_uint(pb1[nt]);
        unsigned u2 = __float_as_uint(pb2[nt]);
        int loc1 = u1 & 127, loc2 = u2 & 127;
        float b1 = __uint_as_float(u1 & 0xFFFFFF80u);
        float b2 = __uint_as_float(u2 & 0xFFFFFF80u);
        int i1 = ((loc1 >> 2) << 4) + lh * 4 + (loc1 & 3);
        int i2 = ((loc2 >> 2) << 4) + lh * 4 + (loc2 & 3);
        float xx = x2p[nt];
#pragma unroll
        for (int off = 16; off <= 32; off <<= 1) {
            float ob1 = __shfl_xor(b1, off, 64);
            int   oi1 = __shfl_xor(i1, off, 64);
            float ob2 = __shfl_xor(b2, off, 64);
            int   oi2 = __shfl_xor(i2, off, 64);
            float oxx = __shfl_xor(xx, off, 64);
            xx += oxx;
            bool to = lessidx(ob1, oi1, b1, i1);
            float w1 = to ? ob1 : b1;  int wi1 = to ? oi1 : i1;
            float l1 = to ? b1 : ob1;  int li1 = to ? i1 : oi1;
            float c2 = to ? ob2 : b2;  int ci2 = to ? oi2 : i2;
            bool t2 = lessidx(l1, li1, c2, ci2);
            b1 = w1; i1 = wi1;
            b2 = t2 ? l1 : c2; i2 = t2 ? li1 : ci2;
        }

        int bw = i1;
        if (lane < 16) {
            double md;
            if (b2 - b1 < 1.2e-2f) {
                const int n = nbase + nt * 16 + lane;
                const float4* xq = (const float4*)(x + (size_t)n * C_DIM);
                const float4* p1 = (const float4*)(emb + (size_t)i1 * C_DIM);
                const float4* p2 = (const float4*)(emb + (size_t)i2 * C_DIM);
                double s1 = 0.0, s2 = 0.0;
#pragma unroll
                for (int i = 0; i < 16; ++i) {
                    float4 xv = xq[i]; float4 a = p1[i]; float4 bq = p2[i];
                    double d;
                    d = (double)xv.x - (double)a.x;  s1 = fma(d, d, s1);
                    d = (double)xv.y - (double)a.y;  s1 = fma(d, d, s1);
                    d = (double)xv.z - (double)a.z;  s1 = fma(d, d, s1);
                    d = (double)xv.w - (double)a.w;  s1 = fma(d, d, s1);
                    d = (double)xv.x - (double)bq.x; s2 = fma(d, d, s2);
                    d = (double)xv.y - (double)bq.y; s2 = fma(d, d, s2);
                    d = (double)xv.z - (double)bq.z; s2 = fma(d, d, s2);
                    d = (double)xv.w - (double)bq.w; s2 = fma(d, d, s2);
                }
                if (s2 < s1 || (s1 == s2 && i2 < i1)) { bw = i2; md = s2; }
                else                                   { md = s1; }
            } else {
                md = (double)xx + (double)b1;
            }
            dsum += md;
        }

        // per-wave gather: 16 vectors x 16 float4 chunks, 4 iters of 64 lanes
        {
            const int v  = lane >> 2;       // vector within group
            const int c0 = lane & 3;        // starting chunk
            const int w  = __shfl(bw, v);   // winner idx of vector v (from lane v)
            const size_t rowb = ((size_t)(nbase + nt * 16 + v)) * 16;
            const float4* ep = (const float4*)emb + (size_t)w * 16;
            float4* op = (float4*)out;
#pragma unroll
            for (int it = 0; it < 4; ++it) op[rowb + c0 + it * 4] = ep[c0 + it * 4];
        }
    }

    // ---- loss partial: lanes 0..15 each hold NT vectors' sum ----
#pragma unroll
    for (int off = 1; off <= 8; off <<= 1) dsum += __shfl_xor(dsum, off, 64);
    if (lane == 0) s_wsum[wid] = dsum;
    __syncthreads();
    if (tid == 0) {
        double t = 0.0;
#pragma unroll
        for (int i = 0; i < BLK / 64; ++i) t += s_wsum[i];
        partials[blockIdx.x] = t;
    }
}

__global__ __launch_bounds__(256) void vq_finalize(const double* __restrict__ partials,
                                                   float* __restrict__ out) {
    double v = partials[threadIdx.x];   // 256 partials
#pragma unroll
    for (int off = 32; off; off >>= 1) v += __shfl_down(v, off, 64);
    __shared__ double ls[4];
    const int lane = threadIdx.x & 63;
    const int wid  = threadIdx.x >> 6;
    if (lane == 0) ls[wid] = v;
    __syncthreads();
    if (threadIdx.x == 0) {
        double t = ls[0] + ls[1] + ls[2] + ls[3];
        double mean = t / (double)((size_t)NVEC * C_DIM);
        out[(size_t)NVEC * C_DIM] = (float)(1.25 * mean);
    }
}

extern "C" void kernel_launch(void* const* d_in, const int* in_sizes, int n_in,
                              void* d_out, int out_size, void* d_ws, size_t ws_size,
                              hipStream_t stream) {
    const float* x   = (const float*)d_in[0];
    const float* emb = (const float*)d_in[1];
    float* out = (float*)d_out;

    float*  e2       = (float*)((char*)d_ws + WS_E2);
    short*  ehi      = (short*)((char*)d_ws + WS_EHI);
    short*  elo      = (short*)((char*)d_ws + WS_ELO);
    double* partials = (double*)((char*)d_ws + WS_PART);

    vq_prep<<<8, 512, 0, stream>>>(emb, e2, ehi, elo);
    vq_main<<<GRID, BLK, 0, stream>>>(x, emb, e2, ehi, elo, out, partials);
    vq_finalize<<<1, 256, 0, stream>>>(partials, out);
}

// Round 5
// 50.664 us; speedup vs baseline: 1.0231x; 1.0231x over previous
//
#include <hip/hip_runtime.h>

// VectorQuantization: x (32,64,64,64) f32, embedding (512,64) f32
// out = [quantized_ste (8388608 f32)] ++ [loss (1 f32)]
//
// score[k,n] = e2[k] - 2*dot(e_k, x_n); argmin_k; gather; loss=1.25*mean dist.
// bf16 3-pass MFMA (hi*hi + lo*hi + hi*lo), packed top-2 + fp64 refine.
// Round 5: 2-batch pipeline per block (x-loads of batch1 in flight during
// batch0 k-loop; batch0 stores drain during batch1 k-loop), k-loop register
// prefetch of next kt fragments, staging OOB fix.

#define C_DIM 64
#define K_EMB 512
#define NVEC (32 * 64 * 64)     // 131072
#define BLK 512                 // 8 waves
#define NPB 512                 // vectors per block (2 batches x 256)
#define NBAT 256                // vectors per batch
#define GRID (NVEC / NPB)       // 256 = 1 block/CU
#define KT (K_EMB / 16)         // 32 k-tiles
#define NT 2                    // 16-vector groups per wave per batch

typedef __attribute__((ext_vector_type(8))) short bf16x8;
typedef __attribute__((ext_vector_type(4))) float f32x4;

// ws layout (bytes)
#define WS_E2   0
#define WS_EHI  4096
#define WS_ELO  (4096 + 65536)
#define WS_PART (4096 + 2 * 65536)

__device__ inline unsigned short f2bf(float f) {
    unsigned u = __float_as_uint(f);
    u += 0x7FFF + ((u >> 16) & 1);   // RNE
    return (unsigned short)(u >> 16);
}
__device__ inline float bf2f(unsigned short h) {
    return __uint_as_float(((unsigned)h) << 16);
}
__device__ inline bool lessidx(float s, int i, float t, int j) {
    return (s < t) || (s == t && i < j);
}

// ---- prep: e2[k]; frag-linear bf16 hi/lo of (-2*emb) ----
// frag layout: region r = kt*2 + s (s = K-step), lane l holds 8 bf16 =
// A[row = kt*16 + (l&15)][c = 32*s + (l>>4)*8 + j], stored at (r*64+l)*8 shorts.
__global__ __launch_bounds__(512) void vq_prep(const float* __restrict__ emb,
                                               float* __restrict__ e2,
                                               short* __restrict__ ehi,
                                               short* __restrict__ elo) {
    const int t = blockIdx.x * 512 + threadIdx.x;   // 0..4095
    const int l = t & 63;
    const int kt2 = t >> 6;                         // kt*2 + s
    const int row = (kt2 >> 1) * 16 + (l & 15);
    const int cb  = (kt2 & 1) * 32 + (l >> 4) * 8;
    const float* src = emb + row * C_DIM + cb;
    bf16x8 vh, vl;
#pragma unroll
    for (int j = 0; j < 8; ++j) {
        float v = -2.0f * src[j];
        unsigned short h = f2bf(v);
        float hf = bf2f(h);
        unsigned short q = f2bf(v - hf);
        vh[j] = (short)h;
        vl[j] = (short)q;
    }
    *(bf16x8*)(ehi + (size_t)t * 8) = vh;
    *(bf16x8*)(elo + (size_t)t * 8) = vl;

    if (t < K_EMB) {
        const float* r = emb + t * C_DIM;
        float s = 0.f;
#pragma unroll
        for (int c = 0; c < C_DIM; ++c) s += r[c] * r[c];
        e2[t] = s;
    }
}

// convert 8 raw float4 (one batch's x slice for this lane) into B-fragments
__device__ __forceinline__ void make_frags(const float4 xr[8],
                                           bf16x8 xh[NT][2], bf16x8 xl[NT][2],
                                           float x2p[NT]) {
#pragma unroll
    for (int nt = 0; nt < NT; ++nt) {
        x2p[nt] = 0.f;
#pragma unroll
        for (int s = 0; s < 2; ++s) {
            float4 a = xr[nt * 4 + s * 2 + 0];
            float4 b = xr[nt * 4 + s * 2 + 1];
            float vv[8] = {a.x, a.y, a.z, a.w, b.x, b.y, b.z, b.w};
#pragma unroll
            for (int j = 0; j < 8; ++j) {
                float v = vv[j];
                x2p[nt] += v * v;
                unsigned short h = f2bf(v);
                float hf = bf2f(h);
                unsigned short q = f2bf(v - hf);
                xh[nt][s][j] = (short)h;
                xl[nt][s][j] = (short)q;
            }
        }
    }
}

// k-loop: 32 tiles, register-prefetched fragments, packed branch-free top-2
__device__ __forceinline__ void kloop(const short* s_hi, const short* s_lo,
                                      const float* s_e2, int lane, int lh,
                                      const bf16x8 xh[NT][2], const bf16x8 xl[NT][2],
                                      float pb1[NT], float pb2[NT]) {
    const bf16x8* hb = (const bf16x8*)s_hi + lane;
    const bf16x8* lb = (const bf16x8*)s_lo + lane;
    bf16x8 ah0 = hb[0], ah1 = hb[64];
    bf16x8 al0 = lb[0], al1 = lb[64];
    float4 ev = *(const float4*)(s_e2 + lh * 4);

#pragma unroll
    for (int nt = 0; nt < NT; ++nt) { pb1[nt] = 1e30f; pb2[nt] = 1e30f; }

#pragma unroll 4
    for (int kt = 0; kt < KT; ++kt) {
        bf16x8 nh0 = ah0, nh1 = ah1, nl0 = al0, nl1 = al1;
        float4 nev = ev;
        if (kt + 1 < KT) {                 // prefetch next tile's fragments
            nh0 = hb[(kt + 1) * 128];
            nh1 = hb[(kt + 1) * 128 + 64];
            nl0 = lb[(kt + 1) * 128];
            nl1 = lb[(kt + 1) * 128 + 64];
            nev = *(const float4*)(s_e2 + (kt + 1) * 16 + lh * 4);
        }

        f32x4 a0 = {ev.x, ev.y, ev.z, ev.w};
        f32x4 a1 = a0;
        a0 = __builtin_amdgcn_mfma_f32_16x16x32_bf16(ah0, xh[0][0], a0, 0, 0, 0);
        a1 = __builtin_amdgcn_mfma_f32_16x16x32_bf16(ah0, xh[1][0], a1, 0, 0, 0);
        a0 = __builtin_amdgcn_mfma_f32_16x16x32_bf16(ah1, xh[0][1], a0, 0, 0, 0);
        a1 = __builtin_amdgcn_mfma_f32_16x16x32_bf16(ah1, xh[1][1], a1, 0, 0, 0);
        a0 = __builtin_amdgcn_mfma_f32_16x16x32_bf16(al0, xh[0][0], a0, 0, 0, 0);
        a1 = __builtin_amdgcn_mfma_f32_16x16x32_bf16(al0, xh[1][0], a1, 0, 0, 0);
        a0 = __builtin_amdgcn_mfma_f32_16x16x32_bf16(al1, xh[0][1], a0, 0, 0, 0);
        a1 = __builtin_amdgcn_mfma_f32_16x16x32_bf16(al1, xh[1][1], a1, 0, 0, 0);
        a0 = __builtin_amdgcn_mfma_f32_16x16x32_bf16(ah0, xl[0][0], a0, 0, 0, 0);
        a1 = __builtin_amdgcn_mfma_f32_16x16x32_bf16(ah0, xl[1][0], a1, 0, 0, 0);
        a0 = __builtin_amdgcn_mfma_f32_16x16x32_bf16(ah1, xl[0][1], a0, 0, 0, 0);
        a1 = __builtin_amdgcn_mfma_f32_16x16x32_bf16(ah1, xl[1][1], a1, 0, 0, 0);

        const unsigned kb4 = (unsigned)(kt * 4);
#define PACKMIN(ACC, NTI)                                                          \
        {                                                                          \
            unsigned q0 = ((__float_as_uint(ACC[0]) + 64u) & 0xFFFFFF80u) | (kb4 + 0); \
            unsigned q1 = ((__float_as_uint(ACC[1]) + 64u) & 0xFFFFFF80u) | (kb4 + 1); \
            unsigned q2 = ((__float_as_uint(ACC[2]) + 64u) & 0xFFFFFF80u) | (kb4 + 2); \
            unsigned q3 = ((__float_as_uint(ACC[3]) + 64u) & 0xFFFFFF80u) | (kb4 + 3); \
            float f0 = __uint_as_float(q0), f1 = __uint_as_float(q1);              \
            float f2 = __uint_as_float(q2), f3 = __uint_as_float(q3);              \
            float lo = fminf(f0, f1), hi = fmaxf(f0, f1);                          \
            pb2[NTI] = fminf(fminf(pb2[NTI], fmaxf(pb1[NTI], lo)), hi);            \
            pb1[NTI] = fminf(pb1[NTI], lo);                                        \
            lo = fminf(f2, f3); hi = fmaxf(f2, f3);                                \
            pb2[NTI] = fminf(fminf(pb2[NTI], fmaxf(pb1[NTI], lo)), hi);            \
            pb1[NTI] = fminf(pb1[NTI], lo);                                        \
        }
        PACKMIN(a0, 0)
        PACKMIN(a1, 1)
#undef PACKMIN
        ah0 = nh0; ah1 = nh1; al0 = nl0; al1 = nl1; ev = nev;
    }
}

// merge/refine/gather/store for one batch; returns loss contribution (lanes 0-15)
__device__ __forceinline__ double epilogue(const float* __restrict__ x,
                                           const float* __restrict__ emb,
                                           float* __restrict__ out,
                                           int nbase, int lane, int lh,
                                           const float pb1[NT], const float pb2[NT],
                                           const float x2p[NT]) {
    double dsum = 0.0;
#pragma unroll
    for (int nt = 0; nt < NT; ++nt) {
        unsigned u1 = __float_as_uint(pb1[nt]);
        unsigned u2 = __float_as_uint(pb2[nt]);
        int loc1 = u1 & 127, loc2 = u2 & 127;
        float b1 = __uint_as_float(u1 & 0xFFFFFF80u);
        float b2 = __uint_as_float(u2 & 0xFFFFFF80u);
        int i1 = ((loc1 >> 2) << 4) + lh * 4 + (loc1 & 3);
        int i2 = ((loc2 >> 2) << 4) + lh * 4 + (loc2 & 3);
        float xx = x2p[nt];
#pragma unroll
        for (int off = 16; off <= 32; off <<= 1) {
            float ob1 = __shfl_xor(b1, off, 64);
            int   oi1 = __shfl_xor(i1, off, 64);
            float ob2 = __shfl_xor(b2, off, 64);
            int   oi2 = __shfl_xor(i2, off, 64);
            float oxx = __shfl_xor(xx, off, 64);
            xx += oxx;
            bool to = lessidx(ob1, oi1, b1, i1);
            float w1 = to ? ob1 : b1;  int wi1 = to ? oi1 : i1;
            float l1 = to ? b1 : ob1;  int li1 = to ? i1 : oi1;
            float c2 = to ? ob2 : b2;  int ci2 = to ? oi2 : i2;
            bool t2 = lessidx(l1, li1, c2, ci2);
            b1 = w1; i1 = wi1;
            b2 = t2 ? l1 : c2; i2 = t2 ? li1 : ci2;
        }

        int bw = i1;
        if (lane < 16) {
            double md;
            if (b2 - b1 < 1.2e-2f) {
                const int n = nbase + nt * 16 + lane;
                const float4* xq = (const float4*)(x + (size_t)n * C_DIM);
                const float4* p1 = (const float4*)(emb + (size_t)i1 * C_DIM);
                const float4* p2 = (const float4*)(emb + (size_t)i2 * C_DIM);
                double s1 = 0.0, s2 = 0.0;
#pragma unroll
                for (int i = 0; i < 16; ++i) {
                    float4 xv = xq[i]; float4 a = p1[i]; float4 bq = p2[i];
                    double d;
                    d = (double)xv.x - (double)a.x;  s1 = fma(d, d, s1);
                    d = (double)xv.y - (double)a.y;  s1 = fma(d, d, s1);
                    d = (double)xv.z - (double)a.z;  s1 = fma(d, d, s1);
                    d = (double)xv.w - (double)a.w;  s1 = fma(d, d, s1);
                    d = (double)xv.x - (double)bq.x; s2 = fma(d, d, s2);
                    d = (double)xv.y - (double)bq.y; s2 = fma(d, d, s2);
                    d = (double)xv.z - (double)bq.z; s2 = fma(d, d, s2);
                    d = (double)xv.w - (double)bq.w; s2 = fma(d, d, s2);
                }
                if (s2 < s1 || (s1 == s2 && i2 < i1)) { bw = i2; md = s2; }
                else                                   { md = s1; }
            } else {
                md = (double)xx + (double)b1;
            }
            dsum += md;
        }

        // per-wave gather: 16 vectors x 16 float4 chunks, 4 iters of 64 lanes
        {
            const int v  = lane >> 2;
            const int c0 = lane & 3;
            const int w  = __shfl(bw, v);
            const size_t rowb = ((size_t)(nbase + nt * 16 + v)) * 16;
            const float4* ep = (const float4*)emb + (size_t)w * 16;
            float4* op = (float4*)out;
#pragma unroll
            for (int it = 0; it < 4; ++it) op[rowb + c0 + it * 4] = ep[c0 + it * 4];
        }
    }
    return dsum;
}

__global__ __launch_bounds__(BLK, 2) void vq_main(
    const float* __restrict__ x,
    const float* __restrict__ emb,
    const float* __restrict__ e2g,
    const short* __restrict__ ehi_g,
    const short* __restrict__ elo_g,
    float* __restrict__ out,
    double* __restrict__ partials)
{
    __shared__ __align__(16) short s_hi[K_EMB * C_DIM];  // 64 KB, frag-linear
    __shared__ __align__(16) short s_lo[K_EMB * C_DIM];  // 64 KB
    __shared__ __align__(16) float s_e2[K_EMB];          // 2 KB
    __shared__ double s_wsum[BLK / 64];

    const int tid  = threadIdx.x;
    const int lane = tid & 63;
    const int wid  = tid >> 6;
    const int lr   = lane & 15;
    const int lh   = lane >> 4;
    const int nbase0 = blockIdx.x * NPB + wid * 32;          // batch 0
    const int nbase1 = blockIdx.x * NPB + NBAT + wid * 32;   // batch 1

    // ---- batch-0 x loads: issue FIRST so they fly during staging ----
    float4 xr0[8];
#pragma unroll
    for (int nt = 0; nt < NT; ++nt) {
        const float* xp = x + (size_t)(nbase0 + nt * 16 + lr) * C_DIM;
#pragma unroll
        for (int s = 0; s < 2; ++s) {
            xr0[nt * 4 + s * 2 + 0] = *(const float4*)(xp + s * 32 + lh * 8);
            xr0[nt * 4 + s * 2 + 1] = *(const float4*)(xp + s * 32 + lh * 8 + 4);
        }
    }

    // ---- stage tables into LDS (linear copy, coalesced) ----
    {
        const float4* srch = (const float4*)ehi_g;
        const float4* srcl = (const float4*)elo_g;
        float4* dsth = (float4*)s_hi;
        float4* dstl = (float4*)s_lo;
#pragma unroll
        for (int i = 0; i < 8; ++i) dsth[tid + i * BLK] = srch[tid + i * BLK];
#pragma unroll
        for (int i = 0; i < 8; ++i) dstl[tid + i * BLK] = srcl[tid + i * BLK];
        if (tid < K_EMB) s_e2[tid] = e2g[tid];
    }
    __syncthreads();

    // ---- batch 0 fragments ----
    bf16x8 xh[NT][2], xl[NT][2];
    float x2p0[NT];
    make_frags(xr0, xh, xl, x2p0);

    // ---- batch-1 x loads: in flight during batch-0 k-loop ----
    float4 xr1[8];
#pragma unroll
    for (int nt = 0; nt < NT; ++nt) {
        const float* xp = x + (size_t)(nbase1 + nt * 16 + lr) * C_DIM;
#pragma unroll
        for (int s = 0; s < 2; ++s) {
            xr1[nt * 4 + s * 2 + 0] = *(const float4*)(xp + s * 32 + lh * 8);
            xr1[nt * 4 + s * 2 + 1] = *(const float4*)(xp + s * 32 + lh * 8 + 4);
        }
    }

    // ---- batch 0: k-loop + epilogue (stores drain during batch-1 k-loop) ----
    float pb1[NT], pb2[NT];
    kloop(s_hi, s_lo, s_e2, lane, lh, xh, xl, pb1, pb2);
    double dsum = epilogue(x, emb, out, nbase0, lane, lh, pb1, pb2, x2p0);

    // ---- batch 1 ----
    float x2p1[NT];
    make_frags(xr1, xh, xl, x2p1);
    kloop(s_hi, s_lo, s_e2, lane, lh, xh, xl, pb1, pb2);
    dsum += epilogue(x, emb, out, nbase1, lane, lh, pb1, pb2, x2p1);

    // ---- loss partial: lanes 0..15 hold per-vector sums ----
#pragma unroll
    for (int off = 1; off <= 8; off <<= 1) dsum += __shfl_xor(dsum, off, 64);
    if (lane == 0) s_wsum[wid] = dsum;
    __syncthreads();
    if (tid == 0) {
        double t = 0.0;
#pragma unroll
        for (int i = 0; i < BLK / 64; ++i) t += s_wsum[i];
        partials[blockIdx.x] = t;
    }
}

__global__ __launch_bounds__(256) void vq_finalize(const double* __restrict__ partials,
                                                   float* __restrict__ out) {
    double v = partials[threadIdx.x];   // 256 partials
#pragma unroll
    for (int off = 32; off; off >>= 1) v += __shfl_down(v, off, 64);
    __shared__ double ls[4];
    const int lane = threadIdx.x & 63;
    const int wid  = threadIdx.x >> 6;
    if (lane == 0) ls[wid] = v;
    __syncthreads();
    if (threadIdx.x == 0) {
        double t = ls[0] + ls[1] + ls[2] + ls[3];
        double mean = t / (double)((size_t)NVEC * C_DIM);
        out[(size_t)NVEC * C_DIM] = (float)(1.25 * mean);
    }
}

extern "C" void kernel_launch(void* const* d_in, const int* in_sizes, int n_in,
                              void* d_out, int out_size, void* d_ws, size_t ws_size,
                              hipStream_t stream) {
    const float* x   = (const float*)d_in[0];
    const float* emb = (const float*)d_in[1];
    float* out = (float*)d_out;

    float*  e2       = (float*)((char*)d_ws + WS_E2);
    short*  ehi      = (short*)((char*)d_ws + WS_EHI);
    short*  elo      = (short*)((char*)d_ws + WS_ELO);
    double* partials = (double*)((char*)d_ws + WS_PART);

    vq_prep<<<8, 512, 0, stream>>>(emb, e2, ehi, elo);
    vq_main<<<GRID, BLK, 0, stream>>>(x, emb, e2, ehi, elo, out, partials);
    vq_finalize<<<1, 256, 0, stream>>>(partials, out);
}